// Round 7
// baseline (3994.997 us; speedup 1.0000x reference)
//
#include <hip/hip_runtime.h>
#include <hip/hip_bf16.h>

#define N_NODES  50000
#define N_EDGES  400000
#define E_TOT    450000   // edges + self loops
#define N_GRAPHS 128
#define D_IN     768
#define D_HID    256

typedef __hip_bfloat16 bf16;

__device__ __forceinline__ float b2f(bf16 v) { return __bfloat162float(v); }
__device__ __forceinline__ float us2f(unsigned short u) { return __uint_as_float((unsigned)u << 16); }
// clamp node index into range — converts residual index bugs into finite wrong answers
__device__ __forceinline__ int clampN(int v) { return min(max(v, 0), N_NODES - 1); }

__device__ __forceinline__ float waveReduceSum(float v) {
#pragma unroll
  for (int o = 32; o > 0; o >>= 1) v += __shfl_down(v, o);
  return v;
}

// 256-thread block reduce; result broadcast to all threads.
__device__ __forceinline__ float blockReduce256(float v, volatile float* buf4) {
  int lane = threadIdx.x & 63, wid = threadIdx.x >> 6;
  v = waveReduceSum(v);
  if (lane == 0) buf4[wid] = v;
  __syncthreads();
  float s = buf4[0] + buf4[1] + buf4[2] + buf4[3];
  __syncthreads();
  return s;
}

// ---------------- index dtype detection + normalization (proved int32, kept as insurance) ----------------
__global__ __launch_bounds__(256) void detect_idx_kernel(
    const int* __restrict__ edge32, int* __restrict__ flagNZ) {
  int t = threadIdx.x;
  int nz = 0;
#pragma unroll
  for (int i = 0; i < 4; ++i) {
    int idx = 2 * (t + i * 256) + 1;  // odd positions; int64 data => all high-halves == 0
    if (edge32[idx] != 0) nz = 1;
  }
  if (nz) atomicOr(flagNZ, 1);
}

__global__ __launch_bounds__(256) void normalize_idx_kernel(
    const void* __restrict__ edge, const void* __restrict__ nbin,
    const int* __restrict__ flagNZ,
    int* __restrict__ src32, int* __restrict__ dst32, int* __restrict__ nb32) {
  bool is64 = (*flagNZ == 0);
  long i = (long)blockIdx.x * 256 + threadIdx.x;
  const int*       e32 = (const int*)edge;
  const long long* e64 = (const long long*)edge;
  const int*       n32 = (const int*)nbin;
  const long long* n64 = (const long long*)nbin;
  if (i < N_EDGES) {
    src32[i] = is64 ? (int)e64[i] : e32[i];
    dst32[i] = is64 ? (int)e64[N_EDGES + i] : e32[N_EDGES + i];
  }
  long j = i - N_EDGES;
  if (j >= 0 && j < N_NODES)
    nb32[j] = is64 ? (int)n64[j] : n32[j];
}

// ---------------- relevance: rel[n] = cos(claim[batch[n]], x[n]) ----------------
__global__ __launch_bounds__(256) void rel_kernel(
    const float* __restrict__ x, const float* __restrict__ claim,
    const int* __restrict__ nb, float* __restrict__ rel) {
  __shared__ float buf[4];
  int n = blockIdx.x;
  int g = min(max(nb[n], 0), N_GRAPHS - 1);
  const float* xr = x + (size_t)n * D_IN;
  const float* cr = claim + (size_t)g * D_IN;
  float dot = 0.f, nx = 0.f, nc = 0.f;
#pragma unroll
  for (int i = 0; i < 3; ++i) {
    int d = threadIdx.x + i * 256;
    float xv = xr[d], cv = cr[d];
    dot += xv * cv; nx += xv * xv; nc += cv * cv;
  }
  dot = blockReduce256(dot, buf);
  nx  = blockReduce256(nx, buf);
  nc  = blockReduce256(nc, buf);
  if (threadIdx.x == 0)
    rel[n] = dot / fmaxf(sqrtf(nx) * sqrtf(nc), 1e-8f);
}

// ------- tiled GEMM: C[M,N] = diag(rowScale) @ A[M,K] @ B[K,N], fp32 in, C stored bf16 -------
template <bool SCALE>
__global__ __launch_bounds__(256) void gemm_kernel(
    const float* __restrict__ A, const float* __restrict__ B,
    const float* __restrict__ rowScale,
    bf16* __restrict__ C, int M, int K, int N) {
  __shared__ float As[64][17];  // [m][k], padded
  __shared__ float Bs[16][64];  // [k][n]
  int tid = threadIdx.x;
  int tx = tid & 15, ty = tid >> 4;
  int mBase = blockIdx.x * 64, nBase = blockIdx.y * 64;
  int ar = tid >> 2;        // 0..63
  int ac = (tid & 3) * 4;   // 0,4,8,12
  int br = tid >> 4;        // 0..15
  int bc = (tid & 15) * 4;  // 0..60
  int mrow = mBase + ar;
  float rm = 1.f;
  if (SCALE && mrow < M) rm = rowScale[mrow];
  float acc[4][4] = {};
  for (int k0 = 0; k0 < K; k0 += 16) {
#pragma unroll
    for (int j = 0; j < 4; ++j) {
      float v = 0.f;
      if (mrow < M) v = A[(size_t)mrow * K + k0 + ac + j] * rm;
      As[ar][ac + j] = v;
    }
#pragma unroll
    for (int j = 0; j < 4; ++j)
      Bs[br][bc + j] = B[(size_t)(k0 + br) * N + nBase + bc + j];
    __syncthreads();
#pragma unroll
    for (int k = 0; k < 16; ++k) {
      float a[4], b[4];
#pragma unroll
      for (int i = 0; i < 4; ++i) a[i] = As[ty * 4 + i][k];
#pragma unroll
      for (int j = 0; j < 4; ++j) b[j] = Bs[k][tx * 4 + j];
#pragma unroll
      for (int i = 0; i < 4; ++i)
#pragma unroll
        for (int j = 0; j < 4; ++j)
          acc[i][j] += a[i] * b[j];
    }
    __syncthreads();
  }
#pragma unroll
  for (int i = 0; i < 4; ++i) {
    int m = mBase + ty * 4 + i;
    if (m < M) {
#pragma unroll
      for (int j = 0; j < 4; ++j)
        C[(size_t)m * N + nBase + tx * 4 + j] = __float2bfloat16(acc[i][j]);
    }
  }
}

// ---------------- per-node attention logits: alpha = h @ a ----------------
__global__ __launch_bounds__(256) void alpha_kernel(
    const bf16* __restrict__ h, const float* __restrict__ a_src,
    const float* __restrict__ a_dst, float* __restrict__ as_, float* __restrict__ ad_) {
  __shared__ float buf[4];
  int n = blockIdx.x;
  float hv = b2f(h[(size_t)n * D_HID + threadIdx.x]);
  float s = hv * a_src[threadIdx.x];
  float d = hv * a_dst[threadIdx.x];
  s = blockReduce256(s, buf);
  d = blockReduce256(d, buf);
  if (threadIdx.x == 0) { as_[n] = s; ad_[n] = d; }
}

// ---------------- segment softmax over edges ----------------
__device__ __forceinline__ unsigned fmapkey(float f) {
  unsigned u = __float_as_uint(f);
  return (u & 0x80000000u) ? ~u : (u | 0x80000000u);
}
__device__ __forceinline__ float funmapkey(unsigned k) {
  unsigned u = (k & 0x80000000u) ? (k & 0x7FFFFFFFu) : ~k;
  return __uint_as_float(u);
}

__global__ __launch_bounds__(256) void edge_logits_kernel(
    const int* __restrict__ src, const int* __restrict__ dst,
    const float* __restrict__ as_, const float* __restrict__ ad_,
    float* __restrict__ elog, unsigned* __restrict__ mkey) {
  int i = blockIdx.x * 256 + threadIdx.x;
  if (i >= E_TOT) return;
  int s, d;
  if (i < N_EDGES) { s = clampN(src[i]); d = clampN(dst[i]); } else { s = d = i - N_EDGES; }
  float e = as_[s] + ad_[d];
  e = e > 0.f ? e : 0.2f * e;  // leaky relu, slope 0.2
  elog[i] = e;
  atomicMax(&mkey[d], fmapkey(e));
}

__global__ __launch_bounds__(256) void edge_exp_kernel(
    const int* __restrict__ dst, const unsigned* __restrict__ mkey,
    float* __restrict__ elog, float* __restrict__ denom) {
  int i = blockIdx.x * 256 + threadIdx.x;
  if (i >= E_TOT) return;
  int d = (i < N_EDGES) ? clampN(dst[i]) : (i - N_EDGES);
  unsigned k = mkey[d];
  float m = (k == 0u) ? 0.f : funmapkey(k);  // k==0 impossible (self-loops) — NaN insurance
  float v = __expf(elog[i] - m);
  elog[i] = v;
  atomicAdd(&denom[d], v);
}

// one wave per edge; lane covers 4 of 256 cols (8B bf16x4 gather)
__global__ __launch_bounds__(256) void edge_aggregate_kernel(
    const int* __restrict__ src, const int* __restrict__ dst,
    const bf16* __restrict__ h, const float* __restrict__ elog,
    const float* __restrict__ denom, float* __restrict__ agg) {
  int w = threadIdx.x >> 6, lane = threadIdx.x & 63;
  long i = (long)blockIdx.x * 4 + w;
  if (i >= E_TOT) return;
  int s, d;
  if (i < N_EDGES) { s = clampN(src[i]); d = clampN(dst[i]); } else { s = d = (int)i - N_EDGES; }
  float attn = elog[i] / fmaxf(denom[d], 1e-30f);
  const ushort4 hv = *(const ushort4*)((const unsigned short*)h + (size_t)s * D_HID + lane * 4);
  float* outp = agg + (size_t)d * D_HID + lane * 4;
  atomicAdd(outp + 0, us2f(hv.x) * attn);
  atomicAdd(outp + 1, us2f(hv.y) * attn);
  atomicAdd(outp + 2, us2f(hv.z) * attn);
  atomicAdd(outp + 3, us2f(hv.w) * attn);
}

// ---------------- batch norm (training stats) ----------------
__global__ __launch_bounds__(256) void bn_stats_kernel(
    const float* __restrict__ h, float* __restrict__ sums, float* __restrict__ sumsq) {
  int col = threadIdx.x;
  float s = 0.f, q = 0.f;
  for (int r = blockIdx.x; r < N_NODES; r += gridDim.x) {
    float v = h[(size_t)r * D_HID + col];
    s += v; q += v * v;
  }
  atomicAdd(&sums[col], s);
  atomicAdd(&sumsq[col], q);
}

__global__ __launch_bounds__(256) void bn_finalize_kernel(
    const float* __restrict__ sums, const float* __restrict__ sumsq,
    const float* __restrict__ gamma, const float* __restrict__ beta,
    float* __restrict__ scale, float* __restrict__ shift) {
  int c = threadIdx.x;
  float mu = sums[c] / N_NODES;
  float var = fmaxf(sumsq[c] / N_NODES - mu * mu, 0.f);
  float sc = gamma[c] * rsqrtf(var + 1e-5f);
  scale[c] = sc;
  shift[c] = beta[c] - mu * sc;
}

__global__ __launch_bounds__(256) void bn_apply_kernel(
    float* __restrict__ a, const float* __restrict__ scale, const float* __restrict__ shift) {
  size_t i = (size_t)blockIdx.x * 256 + threadIdx.x;
  int c = threadIdx.x;  // row stride 256 == blockDim
  a[i] = fmaxf(a[i] * scale[c] + shift[c], 0.f);
}

// ---------------- mean pool (node_batch is sorted) + b2 + relu ----------------
__global__ __launch_bounds__(256) void pool_kernel(
    const float* __restrict__ h, const float* __restrict__ bias2,
    const int* __restrict__ nb, float* __restrict__ pooled) {
  int col = threadIdx.x;
  float bias = bias2[col];
  int chunk = (N_NODES + gridDim.x - 1) / gridDim.x;
  int r0 = blockIdx.x * chunk;
  int r1 = min(N_NODES, r0 + chunk);
  float acc = 0.f; int cur = -1;
  for (int r = r0; r < r1; ++r) {
    int g = min(max(nb[r], 0), N_GRAPHS - 1);
    if (g != cur) {
      if (cur >= 0) atomicAdd(&pooled[(size_t)cur * D_HID + col], acc);
      acc = 0.f; cur = g;
    }
    acc += fmaxf(h[(size_t)r * D_HID + col] + bias, 0.f);
  }
  if (cur >= 0) atomicAdd(&pooled[(size_t)cur * D_HID + col], acc);
}

__global__ __launch_bounds__(256) void count_kernel(
    const int* __restrict__ nb, float* __restrict__ counts) {
  __shared__ int cnt[N_GRAPHS];
  for (int i = threadIdx.x; i < N_GRAPHS; i += 256) cnt[i] = 0;
  __syncthreads();
  int n = blockIdx.x * 256 + threadIdx.x;
  if (n < N_NODES) atomicAdd(&cnt[min(max(nb[n], 0), N_GRAPHS - 1)], 1);
  __syncthreads();
  for (int i = threadIdx.x; i < N_GRAPHS; i += 256)
    if (cnt[i]) atomicAdd(&counts[i], (float)cnt[i]);
}

// ---------------- classifier: out[g] = [pooled/count, claim] . clf_W + clf_b ----------------
// OUTPUT IS FP32: reference returns float32; d_out decoded per reference output dtype.
__global__ __launch_bounds__(256) void clf_kernel(
    const float* __restrict__ pooled, const float* __restrict__ counts,
    const float* __restrict__ claim, const float* __restrict__ clfW,
    const float* __restrict__ clfb, float* __restrict__ out) {
  __shared__ float buf[4];
  int g = blockIdx.x;
  float inv = 1.f / fmaxf(counts[g], 1.f);
  float p = 0.f;
  for (int d = threadIdx.x; d < (D_HID + D_IN); d += 256) {
    float w = clfW[d];
    float v = (d < D_HID) ? pooled[(size_t)g * D_HID + d] * inv
                          : claim[(size_t)g * D_IN + (d - D_HID)];
    p += v * w;
  }
  p = blockReduce256(p, buf);
  if (threadIdx.x == 0) out[g] = p + clfb[0];
}

extern "C" void kernel_launch(void* const* d_in, const int* in_sizes, int n_in,
                              void* d_out, int out_size, void* d_ws, size_t ws_size,
                              hipStream_t stream) {
  // Float tensors fp32 (R5: NaN vanished with fp32 reads). Indices int32 (R6: detector).
  // Output fp32 (R5/R6: bf16-packed writes decoded as fp32 gave the deterministic 2.699).
  const float* claim = (const float*)d_in[0];
  const float* x     = (const float*)d_in[1];
  const void*  edge  = d_in[2];
  const void*  nbin  = d_in[3];
  const float* W1    = (const float*)d_in[4];
  const float* as1   = (const float*)d_in[5];
  const float* ad1   = (const float*)d_in[6];
  // d_in[7] = b1: constant shift cancels exactly in BatchNorm -> unused
  const float* W2    = (const float*)d_in[8];
  const float* as2   = (const float*)d_in[9];
  const float* ad2   = (const float*)d_in[10];
  const float* b2v   = (const float*)d_in[11];
  const float* gamma = (const float*)d_in[12];
  const float* beta  = (const float*)d_in[13];
  const float* clfW  = (const float*)d_in[14];
  const float* clfb  = (const float*)d_in[15];
  float* out = (float*)d_out;

  // ---- workspace: smalls first. Total ~83.2 MB ----
  char* wsb = (char*)d_ws;
  size_t off = 0;
  auto alloc = [&](size_t bytes) -> char* {
    char* p = wsb + off;
    off = (off + bytes + 255) & ~(size_t)255;
    return p;
  };
  int*   flagNZ = (int*)alloc(sizeof(int));
  int*   src32  = (int*)alloc((size_t)N_EDGES * sizeof(int));
  int*   dst32  = (int*)alloc((size_t)N_EDGES * sizeof(int));
  int*   nb32   = (int*)alloc((size_t)N_NODES * sizeof(int));
  float* rel    = (float*)alloc((size_t)N_NODES * sizeof(float));
  float* alphas = (float*)alloc((size_t)N_NODES * sizeof(float));
  float* alphad = (float*)alloc((size_t)N_NODES * sizeof(float));
  unsigned* mkey= (unsigned*)alloc((size_t)N_NODES * sizeof(unsigned));
  float* denom  = (float*)alloc((size_t)N_NODES * sizeof(float));
  float* elog   = (float*)alloc((size_t)E_TOT * sizeof(float));
  float* bnsums = (float*)alloc(D_HID * sizeof(float));
  float* bnsq   = (float*)alloc(D_HID * sizeof(float));
  float* bnscale= (float*)alloc(D_HID * sizeof(float));
  float* bnshift= (float*)alloc(D_HID * sizeof(float));
  float* pooled = (float*)alloc((size_t)N_GRAPHS * D_HID * sizeof(float));
  float* counts = (float*)alloc((size_t)N_GRAPHS * sizeof(float));
  float* agg    = (float*)alloc((size_t)N_NODES * D_HID * sizeof(float)); // fp32: agg1 then agg2 (51.2MB)
  bf16*  h      = (bf16*) alloc((size_t)N_NODES * D_HID * sizeof(bf16));  // bf16: h1 then h2 (25.6MB)

  // ---- index normalization (dtype-proof) ----
  hipMemsetAsync(flagNZ, 0, sizeof(int), stream);
  detect_idx_kernel<<<1, 256, 0, stream>>>((const int*)edge, flagNZ);
  normalize_idx_kernel<<<(N_EDGES + N_NODES + 255) / 256, 256, 0, stream>>>(
      edge, nbin, flagNZ, src32, dst32, nb32);

  // ---- layer 1 init ----
  hipMemsetAsync(mkey, 0, (size_t)N_NODES * 4, stream);
  hipMemsetAsync(denom, 0, (size_t)N_NODES * 4, stream);
  hipMemsetAsync(agg, 0, (size_t)N_NODES * D_HID * 4, stream);
  hipMemsetAsync(bnsums, 0, D_HID * 4, stream);
  hipMemsetAsync(bnsq, 0, D_HID * 4, stream);

  rel_kernel<<<N_NODES, 256, 0, stream>>>(x, claim, nb32, rel);

  dim3 gemmGrid((N_NODES + 63) / 64, D_HID / 64);
  gemm_kernel<true><<<gemmGrid, 256, 0, stream>>>(x, W1, rel, h, N_NODES, D_IN, D_HID);
  alpha_kernel<<<N_NODES, 256, 0, stream>>>(h, as1, ad1, alphas, alphad);

  int egrid = (E_TOT + 255) / 256;
  edge_logits_kernel<<<egrid, 256, 0, stream>>>(src32, dst32, alphas, alphad, elog, mkey);
  edge_exp_kernel<<<egrid, 256, 0, stream>>>(dst32, mkey, elog, denom);
  edge_aggregate_kernel<<<(E_TOT + 3) / 4, 256, 0, stream>>>(src32, dst32, h, elog, denom, agg);

  bn_stats_kernel<<<256, 256, 0, stream>>>(agg, bnsums, bnsq);
  bn_finalize_kernel<<<1, 256, 0, stream>>>(bnsums, bnsq, gamma, beta, bnscale, bnshift);
  bn_apply_kernel<<<N_NODES, 256, 0, stream>>>(agg, bnscale, bnshift);

  // ---- layer 2: h buffer becomes h2 (h1 dead after layer-1 aggregation) ----
  gemm_kernel<false><<<gemmGrid, 256, 0, stream>>>(agg, W2, nullptr, h, N_NODES, D_HID, D_HID);
  alpha_kernel<<<N_NODES, 256, 0, stream>>>(h, as2, ad2, alphas, alphad);

  hipMemsetAsync(mkey, 0, (size_t)N_NODES * 4, stream);
  hipMemsetAsync(denom, 0, (size_t)N_NODES * 4, stream);
  hipMemsetAsync(agg, 0, (size_t)N_NODES * D_HID * 4, stream);
  hipMemsetAsync(pooled, 0, (size_t)N_GRAPHS * D_HID * 4, stream);
  hipMemsetAsync(counts, 0, (size_t)N_GRAPHS * 4, stream);

  edge_logits_kernel<<<egrid, 256, 0, stream>>>(src32, dst32, alphas, alphad, elog, mkey);
  edge_exp_kernel<<<egrid, 256, 0, stream>>>(dst32, mkey, elog, denom);
  edge_aggregate_kernel<<<(E_TOT + 3) / 4, 256, 0, stream>>>(src32, dst32, h, elog, denom, agg);

  pool_kernel<<<256, 256, 0, stream>>>(agg, b2v, nb32, pooled);
  count_kernel<<<(N_NODES + 255) / 256, 256, 0, stream>>>(nb32, counts);
  clf_kernel<<<N_GRAPHS, 256, 0, stream>>>(pooled, counts, claim, clfW, clfb, out);
}

// Round 8
// 1191.641 us; speedup vs baseline: 3.3525x; 3.3525x over previous
//
#include <hip/hip_runtime.h>
#include <hip/hip_bf16.h>

#define N_NODES  50000
#define N_EDGES  400000
#define E_TOT    450000   // edges + self loops
#define N_GRAPHS 128
#define D_IN     768
#define D_HID    256

typedef __hip_bfloat16 bf16;

__device__ __forceinline__ float b2f(bf16 v) { return __bfloat162float(v); }
__device__ __forceinline__ float us2f(unsigned short u) { return __uint_as_float((unsigned)u << 16); }
__device__ __forceinline__ int clampN(int v) { return min(max(v, 0), N_NODES - 1); }

__device__ __forceinline__ float waveReduceSum(float v) {
#pragma unroll
  for (int o = 32; o > 0; o >>= 1) v += __shfl_down(v, o);
  return v;
}

__device__ __forceinline__ float blockReduce256(float v, volatile float* buf4) {
  int lane = threadIdx.x & 63, wid = threadIdx.x >> 6;
  v = waveReduceSum(v);
  if (lane == 0) buf4[wid] = v;
  __syncthreads();
  float s = buf4[0] + buf4[1] + buf4[2] + buf4[3];
  __syncthreads();
  return s;
}

// ---------------- index dtype detection + normalization ----------------
__global__ __launch_bounds__(256) void detect_idx_kernel(
    const int* __restrict__ edge32, int* __restrict__ flagNZ) {
  int t = threadIdx.x;
  int nz = 0;
#pragma unroll
  for (int i = 0; i < 4; ++i) {
    int idx = 2 * (t + i * 256) + 1;
    if (edge32[idx] != 0) nz = 1;
  }
  if (nz) atomicOr(flagNZ, 1);
}

__global__ __launch_bounds__(256) void normalize_idx_kernel(
    const void* __restrict__ edge, const void* __restrict__ nbin,
    const int* __restrict__ flagNZ,
    int* __restrict__ src32, int* __restrict__ dst32, int* __restrict__ nb32) {
  bool is64 = (*flagNZ == 0);
  long i = (long)blockIdx.x * 256 + threadIdx.x;
  const int*       e32 = (const int*)edge;
  const long long* e64 = (const long long*)edge;
  const int*       n32 = (const int*)nbin;
  const long long* n64 = (const long long*)nbin;
  if (i < N_EDGES) {
    src32[i] = clampN(is64 ? (int)e64[i] : e32[i]);
    dst32[i] = clampN(is64 ? (int)e64[N_EDGES + i] : e32[N_EDGES + i]);
  }
  long j = i - N_EDGES;
  if (j >= 0 && j < N_NODES)
    nb32[j] = min(max(is64 ? (int)n64[j] : n32[j], 0), N_GRAPHS - 1);
}

// ---------------- CSR build: histogram -> scan -> scatter ----------------
__global__ __launch_bounds__(256) void hist_kernel(
    const int* __restrict__ dst, int* __restrict__ deg) {
  int i = blockIdx.x * 256 + threadIdx.x;
  if (i >= E_TOT) return;
  int d = (i < N_EDGES) ? dst[i] : (i - N_EDGES);
  atomicAdd(&deg[d], 1);
}

// single block of 256; shuffle-based inclusive scan per 256-chunk with carried prefix
__global__ __launch_bounds__(256) void scan_kernel(
    const int* __restrict__ deg, int* __restrict__ rowptr, int* __restrict__ pos) {
  __shared__ int wsum[4];
  __shared__ int carrySh;
  int lane = threadIdx.x & 63, wid = threadIdx.x >> 6;
  if (threadIdx.x == 0) { carrySh = 0; rowptr[0] = 0; }
  __syncthreads();
  for (int base = 0; base < N_NODES; base += 256) {
    int i = base + threadIdx.x;
    int v = (i < N_NODES) ? deg[i] : 0;
    int sc = v;
#pragma unroll
    for (int o = 1; o < 64; o <<= 1) {
      int t = __shfl_up(sc, o);
      if (lane >= o) sc += t;
    }
    if (lane == 63) wsum[wid] = sc;
    __syncthreads();
    int woff = 0;
    for (int w = 0; w < wid; ++w) woff += wsum[w];
    int carry = carrySh;
    int incl = carry + woff + sc;
    if (i < N_NODES) { rowptr[i + 1] = incl; pos[i] = incl - v; }
    // total for this chunk = carry + sum of all wave sums
    __syncthreads();
    if (threadIdx.x == 255) carrySh = incl;
    __syncthreads();
  }
}

__global__ __launch_bounds__(256) void scatter_kernel(
    const int* __restrict__ src, const int* __restrict__ dst,
    int* __restrict__ pos, int* __restrict__ srcS) {
  int i = blockIdx.x * 256 + threadIdx.x;
  if (i >= E_TOT) return;
  int s, d;
  if (i < N_EDGES) { s = src[i]; d = dst[i]; } else { s = d = i - N_EDGES; }
  int j = atomicAdd(&pos[d], 1);
  srcS[j] = s;
}

// ---------------- relevance: rel[n] = cos(claim[batch[n]], x[n]) ----------------
__global__ __launch_bounds__(256) void rel_kernel(
    const float* __restrict__ x, const float* __restrict__ claim,
    const int* __restrict__ nb, float* __restrict__ rel) {
  __shared__ float buf[4];
  int n = blockIdx.x;
  int g = nb[n];
  const float* xr = x + (size_t)n * D_IN;
  const float* cr = claim + (size_t)g * D_IN;
  float dot = 0.f, nx = 0.f, nc = 0.f;
#pragma unroll
  for (int i = 0; i < 3; ++i) {
    int d = threadIdx.x + i * 256;
    float xv = xr[d], cv = cr[d];
    dot += xv * cv; nx += xv * xv; nc += cv * cv;
  }
  dot = blockReduce256(dot, buf);
  nx  = blockReduce256(nx, buf);
  nc  = blockReduce256(nc, buf);
  if (threadIdx.x == 0)
    rel[n] = dot / fmaxf(sqrtf(nx) * sqrtf(nc), 1e-8f);
}

// ------- tiled GEMM: C[M,N] = diag(rowScale) @ A[M,K] @ B[K,N], fp32 in, C stored bf16 -------
template <bool SCALE>
__global__ __launch_bounds__(256) void gemm_kernel(
    const float* __restrict__ A, const float* __restrict__ B,
    const float* __restrict__ rowScale,
    bf16* __restrict__ C, int M, int K, int N) {
  __shared__ float As[64][17];
  __shared__ float Bs[16][64];
  int tid = threadIdx.x;
  int tx = tid & 15, ty = tid >> 4;
  int mBase = blockIdx.x * 64, nBase = blockIdx.y * 64;
  int ar = tid >> 2;
  int ac = (tid & 3) * 4;
  int br = tid >> 4;
  int bc = (tid & 15) * 4;
  int mrow = mBase + ar;
  float rm = 1.f;
  if (SCALE && mrow < M) rm = rowScale[mrow];
  float acc[4][4] = {};
  for (int k0 = 0; k0 < K; k0 += 16) {
#pragma unroll
    for (int j = 0; j < 4; ++j) {
      float v = 0.f;
      if (mrow < M) v = A[(size_t)mrow * K + k0 + ac + j] * rm;
      As[ar][ac + j] = v;
    }
#pragma unroll
    for (int j = 0; j < 4; ++j)
      Bs[br][bc + j] = B[(size_t)(k0 + br) * N + nBase + bc + j];
    __syncthreads();
#pragma unroll
    for (int k = 0; k < 16; ++k) {
      float a[4], b[4];
#pragma unroll
      for (int i = 0; i < 4; ++i) a[i] = As[ty * 4 + i][k];
#pragma unroll
      for (int j = 0; j < 4; ++j) b[j] = Bs[k][tx * 4 + j];
#pragma unroll
      for (int i = 0; i < 4; ++i)
#pragma unroll
        for (int j = 0; j < 4; ++j)
          acc[i][j] += a[i] * b[j];
    }
    __syncthreads();
  }
#pragma unroll
  for (int i = 0; i < 4; ++i) {
    int m = mBase + ty * 4 + i;
    if (m < M) {
#pragma unroll
      for (int j = 0; j < 4; ++j)
        C[(size_t)m * N + nBase + tx * 4 + j] = __float2bfloat16(acc[i][j]);
    }
  }
}

// ---------------- per-node attention logits: alpha = h @ a ----------------
__global__ __launch_bounds__(256) void alpha_kernel(
    const bf16* __restrict__ h, const float* __restrict__ a_src,
    const float* __restrict__ a_dst, float* __restrict__ as_, float* __restrict__ ad_) {
  __shared__ float buf[4];
  int n = blockIdx.x;
  float hv = b2f(h[(size_t)n * D_HID + threadIdx.x]);
  float s = hv * a_src[threadIdx.x];
  float d = hv * a_dst[threadIdx.x];
  s = blockReduce256(s, buf);
  d = blockReduce256(d, buf);
  if (threadIdx.x == 0) { as_[n] = s; ad_[n] = d; }
}

// ---------------- fused GAT softmax + aggregate: one wave per dst node ----------------
// Replaces edge_logits/edge_exp/edge_aggregate; no atomics, writes agg row once.
__global__ __launch_bounds__(256) void gat_agg_kernel(
    const int* __restrict__ rowptr, const int* __restrict__ srcS,
    const float* __restrict__ as_, const float* __restrict__ ad_,
    const bf16* __restrict__ h, float* __restrict__ agg) {
  int wid = threadIdx.x >> 6, lane = threadIdx.x & 63;
  int n = blockIdx.x * 4 + wid;
  if (n >= N_NODES) return;
  int start = rowptr[n], end = rowptr[n + 1];  // end>start guaranteed (self-loop)
  float adn = ad_[n];
  // pass A: segment max (lanes parallel over edges)
  float m = -1e30f;
  for (int j0 = start; j0 < end; j0 += 64) {
    int j = j0 + lane;
    if (j < end) {
      float e = as_[srcS[j]] + adn;
      e = e > 0.f ? e : 0.2f * e;
      m = fmaxf(m, e);
    }
  }
#pragma unroll
  for (int o = 32; o > 0; o >>= 1) m = fmaxf(m, __shfl_xor(m, o));
  // pass B: denominator
  float ssum = 0.f;
  for (int j0 = start; j0 < end; j0 += 64) {
    int j = j0 + lane;
    if (j < end) {
      float e = as_[srcS[j]] + adn;
      e = e > 0.f ? e : 0.2f * e;
      ssum += __expf(e - m);
    }
  }
#pragma unroll
  for (int o = 32; o > 0; o >>= 1) ssum += __shfl_xor(ssum, o);
  float inv = 1.f / ssum;  // ssum >= exp(0) = 1 at the max edge
  // pass C: serial over edges, lanes parallel over 256 cols (4 each)
  float a0 = 0.f, a1 = 0.f, a2 = 0.f, a3 = 0.f;
  const unsigned short* hp = (const unsigned short*)h;
  for (int j = start; j < end; ++j) {
    int s = srcS[j];                        // wave-uniform -> broadcast load
    float e = as_[s] + adn;
    e = e > 0.f ? e : 0.2f * e;
    float attn = __expf(e - m) * inv;
    const ushort4 hv = *(const ushort4*)(hp + (size_t)s * D_HID + lane * 4);
    a0 += us2f(hv.x) * attn;
    a1 += us2f(hv.y) * attn;
    a2 += us2f(hv.z) * attn;
    a3 += us2f(hv.w) * attn;
  }
  float4 o4 = {a0, a1, a2, a3};
  *(float4*)(agg + (size_t)n * D_HID + lane * 4) = o4;
}

// ---------------- batch norm (training stats) ----------------
__global__ __launch_bounds__(256) void bn_stats_kernel(
    const float* __restrict__ h, float* __restrict__ sums, float* __restrict__ sumsq) {
  int col = threadIdx.x;
  float s = 0.f, q = 0.f;
  for (int r = blockIdx.x; r < N_NODES; r += gridDim.x) {
    float v = h[(size_t)r * D_HID + col];
    s += v; q += v * v;
  }
  atomicAdd(&sums[col], s);
  atomicAdd(&sumsq[col], q);
}

__global__ __launch_bounds__(256) void bn_finalize_kernel(
    const float* __restrict__ sums, const float* __restrict__ sumsq,
    const float* __restrict__ gamma, const float* __restrict__ beta,
    float* __restrict__ scale, float* __restrict__ shift) {
  int c = threadIdx.x;
  float mu = sums[c] / N_NODES;
  float var = fmaxf(sumsq[c] / N_NODES - mu * mu, 0.f);
  float sc = gamma[c] * rsqrtf(var + 1e-5f);
  scale[c] = sc;
  shift[c] = beta[c] - mu * sc;
}

__global__ __launch_bounds__(256) void bn_apply_kernel(
    float* __restrict__ a, const float* __restrict__ scale, const float* __restrict__ shift) {
  size_t i = (size_t)blockIdx.x * 256 + threadIdx.x;
  int c = threadIdx.x;
  a[i] = fmaxf(a[i] * scale[c] + shift[c], 0.f);
}

// ---------------- mean pool (node_batch sorted) + b2 + relu ----------------
__global__ __launch_bounds__(256) void pool_kernel(
    const float* __restrict__ h, const float* __restrict__ bias2,
    const int* __restrict__ nb, float* __restrict__ pooled) {
  int col = threadIdx.x;
  float bias = bias2[col];
  int chunk = (N_NODES + gridDim.x - 1) / gridDim.x;
  int r0 = blockIdx.x * chunk;
  int r1 = min(N_NODES, r0 + chunk);
  float acc = 0.f; int cur = -1;
  for (int r = r0; r < r1; ++r) {
    int g = nb[r];
    if (g != cur) {
      if (cur >= 0) atomicAdd(&pooled[(size_t)cur * D_HID + col], acc);
      acc = 0.f; cur = g;
    }
    acc += fmaxf(h[(size_t)r * D_HID + col] + bias, 0.f);
  }
  if (cur >= 0) atomicAdd(&pooled[(size_t)cur * D_HID + col], acc);
}

__global__ __launch_bounds__(256) void count_kernel(
    const int* __restrict__ nb, float* __restrict__ counts) {
  __shared__ int cnt[N_GRAPHS];
  for (int i = threadIdx.x; i < N_GRAPHS; i += 256) cnt[i] = 0;
  __syncthreads();
  int n = blockIdx.x * 256 + threadIdx.x;
  if (n < N_NODES) atomicAdd(&cnt[nb[n]], 1);
  __syncthreads();
  for (int i = threadIdx.x; i < N_GRAPHS; i += 256)
    if (cnt[i]) atomicAdd(&counts[i], (float)cnt[i]);
}

// ---------------- classifier (OUTPUT FP32) ----------------
__global__ __launch_bounds__(256) void clf_kernel(
    const float* __restrict__ pooled, const float* __restrict__ counts,
    const float* __restrict__ claim, const float* __restrict__ clfW,
    const float* __restrict__ clfb, float* __restrict__ out) {
  __shared__ float buf[4];
  int g = blockIdx.x;
  float inv = 1.f / fmaxf(counts[g], 1.f);
  float p = 0.f;
  for (int d = threadIdx.x; d < (D_HID + D_IN); d += 256) {
    float w = clfW[d];
    float v = (d < D_HID) ? pooled[(size_t)g * D_HID + d] * inv
                          : claim[(size_t)g * D_IN + (d - D_HID)];
    p += v * w;
  }
  p = blockReduce256(p, buf);
  if (threadIdx.x == 0) out[g] = p + clfb[0];
}

extern "C" void kernel_launch(void* const* d_in, const int* in_sizes, int n_in,
                              void* d_out, int out_size, void* d_ws, size_t ws_size,
                              hipStream_t stream) {
  const float* claim = (const float*)d_in[0];
  const float* x     = (const float*)d_in[1];
  const void*  edge  = d_in[2];
  const void*  nbin  = d_in[3];
  const float* W1    = (const float*)d_in[4];
  const float* as1   = (const float*)d_in[5];
  const float* ad1   = (const float*)d_in[6];
  // d_in[7] = b1: cancels in BatchNorm
  const float* W2    = (const float*)d_in[8];
  const float* as2   = (const float*)d_in[9];
  const float* ad2   = (const float*)d_in[10];
  const float* b2v   = (const float*)d_in[11];
  const float* gamma = (const float*)d_in[12];
  const float* beta  = (const float*)d_in[13];
  const float* clfW  = (const float*)d_in[14];
  const float* clfb  = (const float*)d_in[15];
  float* out = (float*)d_out;

  char* wsb = (char*)d_ws;
  size_t off = 0;
  auto alloc = [&](size_t bytes) -> char* {
    char* p = wsb + off;
    off = (off + bytes + 255) & ~(size_t)255;
    return p;
  };
  int*   flagNZ = (int*)alloc(sizeof(int));
  int*   src32  = (int*)alloc((size_t)N_EDGES * sizeof(int));
  int*   dst32  = (int*)alloc((size_t)N_EDGES * sizeof(int));
  int*   nb32   = (int*)alloc((size_t)N_NODES * sizeof(int));
  int*   deg    = (int*)alloc((size_t)N_NODES * sizeof(int));
  int*   rowptr = (int*)alloc((size_t)(N_NODES + 1) * sizeof(int));
  int*   pos    = (int*)alloc((size_t)N_NODES * sizeof(int));
  int*   srcS   = (int*)alloc((size_t)E_TOT * sizeof(int));
  float* rel    = (float*)alloc((size_t)N_NODES * sizeof(float));
  float* alphas = (float*)alloc((size_t)N_NODES * sizeof(float));
  float* alphad = (float*)alloc((size_t)N_NODES * sizeof(float));
  float* bnsums = (float*)alloc(D_HID * sizeof(float));
  float* bnsq   = (float*)alloc(D_HID * sizeof(float));
  float* bnscale= (float*)alloc(D_HID * sizeof(float));
  float* bnshift= (float*)alloc(D_HID * sizeof(float));
  float* pooled = (float*)alloc((size_t)N_GRAPHS * D_HID * sizeof(float));
  float* counts = (float*)alloc((size_t)N_GRAPHS * sizeof(float));
  float* agg    = (float*)alloc((size_t)N_NODES * D_HID * sizeof(float)); // agg1 then agg2
  bf16*  h      = (bf16*) alloc((size_t)N_NODES * D_HID * sizeof(bf16));  // h1 then h2

  // ---- index normalization + CSR build (once, reused by both layers) ----
  hipMemsetAsync(flagNZ, 0, sizeof(int), stream);
  detect_idx_kernel<<<1, 256, 0, stream>>>((const int*)edge, flagNZ);
  normalize_idx_kernel<<<(N_EDGES + N_NODES + 255) / 256, 256, 0, stream>>>(
      edge, nbin, flagNZ, src32, dst32, nb32);
  hipMemsetAsync(deg, 0, (size_t)N_NODES * sizeof(int), stream);
  int egrid = (E_TOT + 255) / 256;
  hist_kernel<<<egrid, 256, 0, stream>>>(dst32, deg);
  scan_kernel<<<1, 256, 0, stream>>>(deg, rowptr, pos);
  scatter_kernel<<<egrid, 256, 0, stream>>>(src32, dst32, pos, srcS);

  hipMemsetAsync(bnsums, 0, D_HID * 4, stream);
  hipMemsetAsync(bnsq, 0, D_HID * 4, stream);
  hipMemsetAsync(pooled, 0, (size_t)N_GRAPHS * D_HID * 4, stream);
  hipMemsetAsync(counts, 0, (size_t)N_GRAPHS * 4, stream);

  // ---- layer 1 ----
  rel_kernel<<<N_NODES, 256, 0, stream>>>(x, claim, nb32, rel);
  dim3 gemmGrid((N_NODES + 63) / 64, D_HID / 64);
  gemm_kernel<true><<<gemmGrid, 256, 0, stream>>>(x, W1, rel, h, N_NODES, D_IN, D_HID);
  alpha_kernel<<<N_NODES, 256, 0, stream>>>(h, as1, ad1, alphas, alphad);
  gat_agg_kernel<<<N_NODES / 4, 256, 0, stream>>>(rowptr, srcS, alphas, alphad, h, agg);

  bn_stats_kernel<<<256, 256, 0, stream>>>(agg, bnsums, bnsq);
  bn_finalize_kernel<<<1, 256, 0, stream>>>(bnsums, bnsq, gamma, beta, bnscale, bnshift);
  bn_apply_kernel<<<N_NODES, 256, 0, stream>>>(agg, bnscale, bnshift);

  // ---- layer 2 ----
  gemm_kernel<false><<<gemmGrid, 256, 0, stream>>>(agg, W2, nullptr, h, N_NODES, D_HID, D_HID);
  alpha_kernel<<<N_NODES, 256, 0, stream>>>(h, as2, ad2, alphas, alphad);
  gat_agg_kernel<<<N_NODES / 4, 256, 0, stream>>>(rowptr, srcS, alphas, alphad, h, agg);

  // ---- pool + classifier ----
  pool_kernel<<<256, 256, 0, stream>>>(agg, b2v, nb32, pooled);
  count_kernel<<<(N_NODES + 255) / 256, 256, 0, stream>>>(nb32, counts);
  clf_kernel<<<N_GRAPHS, 256, 0, stream>>>(pooled, counts, claim, clfW, clfb, out);
}

// Round 9
// 938.089 us; speedup vs baseline: 4.2587x; 1.2703x over previous
//
#include <hip/hip_runtime.h>
#include <hip/hip_bf16.h>

#define N_NODES  50000
#define N_EDGES  400000
#define E_TOT    450000   // edges + self loops
#define N_GRAPHS 128
#define D_IN     768
#define D_HID    256

typedef __hip_bfloat16 bf16;
typedef __attribute__((ext_vector_type(8))) short short8;
typedef __attribute__((ext_vector_type(4))) float f32x4;

__device__ __forceinline__ float b2f(bf16 v) { return __bfloat162float(v); }
__device__ __forceinline__ float us2f(unsigned short u) { return __uint_as_float((unsigned)u << 16); }
__device__ __forceinline__ int clampN(int v) { return min(max(v, 0), N_NODES - 1); }
// fp32 -> bf16 bits (RNE), as short for MFMA fragments
__device__ __forceinline__ short f2bs(float f) {
  unsigned u = __float_as_uint(f);
  return (short)((u + 0x7FFFu + ((u >> 16) & 1u)) >> 16);
}

__device__ __forceinline__ float waveReduceSum(float v) {
#pragma unroll
  for (int o = 32; o > 0; o >>= 1) v += __shfl_down(v, o);
  return v;
}

__device__ __forceinline__ float blockReduce256(float v, volatile float* buf4) {
  int lane = threadIdx.x & 63, wid = threadIdx.x >> 6;
  v = waveReduceSum(v);
  if (lane == 0) buf4[wid] = v;
  __syncthreads();
  float s = buf4[0] + buf4[1] + buf4[2] + buf4[3];
  __syncthreads();
  return s;
}

// ---------------- index dtype detection + normalization ----------------
__global__ __launch_bounds__(256) void detect_idx_kernel(
    const int* __restrict__ edge32, int* __restrict__ flagNZ) {
  int t = threadIdx.x;
  int nz = 0;
#pragma unroll
  for (int i = 0; i < 4; ++i) {
    int idx = 2 * (t + i * 256) + 1;
    if (edge32[idx] != 0) nz = 1;
  }
  if (nz) atomicOr(flagNZ, 1);
}

__global__ __launch_bounds__(256) void normalize_idx_kernel(
    const void* __restrict__ edge, const void* __restrict__ nbin,
    const int* __restrict__ flagNZ,
    int* __restrict__ src32, int* __restrict__ dst32, int* __restrict__ nb32) {
  bool is64 = (*flagNZ == 0);
  long i = (long)blockIdx.x * 256 + threadIdx.x;
  const int*       e32 = (const int*)edge;
  const long long* e64 = (const long long*)edge;
  const int*       n32 = (const int*)nbin;
  const long long* n64 = (const long long*)nbin;
  if (i < N_EDGES) {
    src32[i] = clampN(is64 ? (int)e64[i] : e32[i]);
    dst32[i] = clampN(is64 ? (int)e64[N_EDGES + i] : e32[N_EDGES + i]);
  }
  long j = i - N_EDGES;
  if (j >= 0 && j < N_NODES)
    nb32[j] = min(max(is64 ? (int)n64[j] : n32[j], 0), N_GRAPHS - 1);
}

// ---------------- CSR build: histogram -> scan -> scatter ----------------
__global__ __launch_bounds__(256) void hist_kernel(
    const int* __restrict__ dst, int* __restrict__ deg) {
  int i = blockIdx.x * 256 + threadIdx.x;
  if (i >= E_TOT) return;
  int d = (i < N_EDGES) ? dst[i] : (i - N_EDGES);
  atomicAdd(&deg[d], 1);
}

__global__ __launch_bounds__(256) void scan_kernel(
    const int* __restrict__ deg, int* __restrict__ rowptr, int* __restrict__ pos) {
  __shared__ int wsum[4];
  __shared__ int carrySh;
  int lane = threadIdx.x & 63, wid = threadIdx.x >> 6;
  if (threadIdx.x == 0) { carrySh = 0; rowptr[0] = 0; }
  __syncthreads();
  for (int base = 0; base < N_NODES; base += 256) {
    int i = base + threadIdx.x;
    int v = (i < N_NODES) ? deg[i] : 0;
    int sc = v;
#pragma unroll
    for (int o = 1; o < 64; o <<= 1) {
      int t = __shfl_up(sc, o);
      if (lane >= o) sc += t;
    }
    if (lane == 63) wsum[wid] = sc;
    __syncthreads();
    int woff = 0;
    for (int w = 0; w < wid; ++w) woff += wsum[w];
    int incl = carrySh + woff + sc;
    if (i < N_NODES) { rowptr[i + 1] = incl; pos[i] = incl - v; }
    __syncthreads();
    if (threadIdx.x == 255) carrySh = incl;
    __syncthreads();
  }
}

__global__ __launch_bounds__(256) void scatter_kernel(
    const int* __restrict__ src, const int* __restrict__ dst,
    int* __restrict__ pos, int* __restrict__ srcS) {
  int i = blockIdx.x * 256 + threadIdx.x;
  if (i >= E_TOT) return;
  int s, d;
  if (i < N_EDGES) { s = src[i]; d = dst[i]; } else { s = d = i - N_EDGES; }
  int j = atomicAdd(&pos[d], 1);
  srcS[j] = s;
}

// ---------------- weight transpose + bf16 convert: WT[n][k] = bf16(W[k][n]) ----------------
__global__ __launch_bounds__(256) void convert_wt_kernel(
    const float* __restrict__ W, short* __restrict__ WT, int K, int N) {
  int i = blockIdx.x * 256 + threadIdx.x;
  if (i >= K * N) return;
  int n = i / K, k = i - n * K;
  WT[i] = f2bs(W[(size_t)k * N + n]);
}

// ---------------- relevance: rel[n] = cos(claim[batch[n]], x[n]) ----------------
__global__ __launch_bounds__(256) void rel_kernel(
    const float* __restrict__ x, const float* __restrict__ claim,
    const int* __restrict__ nb, float* __restrict__ rel) {
  __shared__ float buf[4];
  int n = blockIdx.x;
  int g = nb[n];
  const float* xr = x + (size_t)n * D_IN;
  const float* cr = claim + (size_t)g * D_IN;
  float dot = 0.f, nx = 0.f, nc = 0.f;
#pragma unroll
  for (int i = 0; i < 3; ++i) {
    int d = threadIdx.x + i * 256;
    float xv = xr[d], cv = cr[d];
    dot += xv * cv; nx += xv * xv; nc += cv * cv;
  }
  dot = blockReduce256(dot, buf);
  nx  = blockReduce256(nx, buf);
  nc  = blockReduce256(nc, buf);
  if (threadIdx.x == 0)
    rel[n] = dot / fmaxf(sqrtf(nx) * sqrtf(nc), 1e-8f);
}

// ---------------- MFMA GEMM: C[M,256] = epi(A[M,K]) @ B[K,256], C bf16 ----------------
// Tile 64x256 per block (4 waves, wave = 16 rows x full N). A staged fp32->bf16 with
// fused epilogue: EPI=0 row-scale (rel); EPI=1 per-col BN scale/shift + ReLU.
// Layouts (HW-verified): A-frag A[m=lane&15][k=quad*8+j]; B-frag B[k=quad*8+j][n=lane&15]
// (from W^T, contiguous k); C/D col=lane&15, row=quad*4+reg.
#define BK 32
template <int EPI>
__global__ __launch_bounds__(256) void mfma_gemm_kernel(
    const float* __restrict__ A, const short* __restrict__ BT,
    const float* __restrict__ rowScale,
    const float* __restrict__ cscale, const float* __restrict__ cshift,
    bf16* __restrict__ C, int M, int K) {
  __shared__ short As[64][BK + 8];    // stride 40 shorts = 80B (16B-aligned rows)
  __shared__ short Bs[256][BK + 8];
  int tid = threadIdx.x;
  int wave = tid >> 6, lane = tid & 63;
  int quad = lane >> 4, l16 = lane & 15;
  int mBase = blockIdx.x * 64;

  f32x4 acc[16] = {};

  int ar = tid >> 2;            // A stage: row 0..63
  int ak = (tid & 3) * 8;       // k offset 0,8,16,24
  int arow = mBase + ar;
  float rm = 1.f;
  if (EPI == 0 && arow < M) rm = rowScale[arow];

  for (int k0 = 0; k0 < K; k0 += BK) {
    // ---- stage A (fp32 -> epi -> bf16) ----
    float av[8];
    if (arow < M) {
      const f32x4* ap = (const f32x4*)(A + (size_t)arow * K + k0 + ak);
      f32x4 v0 = ap[0], v1 = ap[1];
      av[0]=v0.x; av[1]=v0.y; av[2]=v0.z; av[3]=v0.w;
      av[4]=v1.x; av[5]=v1.y; av[6]=v1.z; av[7]=v1.w;
      if (EPI == 0) {
#pragma unroll
        for (int j = 0; j < 8; ++j) av[j] *= rm;
      } else {
#pragma unroll
        for (int j = 0; j < 8; ++j) {
          int kk = k0 + ak + j;
          av[j] = fmaxf(av[j] * cscale[kk] + cshift[kk], 0.f);
        }
      }
    } else {
#pragma unroll
      for (int j = 0; j < 8; ++j) av[j] = 0.f;
    }
    short8 a8;
#pragma unroll
    for (int j = 0; j < 8; ++j) a8[j] = f2bs(av[j]);
    *(short8*)&As[ar][ak] = a8;
    // ---- stage B (bf16 W^T row per thread) ----
    {
      const short8* bp = (const short8*)(BT + (size_t)tid * K + k0);
#pragma unroll
      for (int j = 0; j < 4; ++j)
        *(short8*)&Bs[tid][j * 8] = bp[j];
    }
    __syncthreads();
    // ---- compute ----
    short8 af = *(short8*)&As[wave * 16 + l16][quad * 8];
#pragma unroll
    for (int nt = 0; nt < 16; ++nt) {
      short8 bf = *(short8*)&Bs[nt * 16 + l16][quad * 8];
      acc[nt] = __builtin_amdgcn_mfma_f32_16x16x32_bf16(af, bf, acc[nt], 0, 0, 0);
    }
    __syncthreads();
  }
  // ---- epilogue store ----
#pragma unroll
  for (int nt = 0; nt < 16; ++nt) {
#pragma unroll
    for (int r = 0; r < 4; ++r) {
      int m = mBase + wave * 16 + quad * 4 + r;
      if (m < M)
        C[(size_t)m * D_HID + nt * 16 + l16] = __float2bfloat16(acc[nt][r]);
    }
  }
}

// ---------------- per-node attention logits: alpha = h @ a ----------------
__global__ __launch_bounds__(256) void alpha_kernel(
    const bf16* __restrict__ h, const float* __restrict__ a_src,
    const float* __restrict__ a_dst, float* __restrict__ as_, float* __restrict__ ad_) {
  __shared__ float buf[4];
  int n = blockIdx.x;
  float hv = b2f(h[(size_t)n * D_HID + threadIdx.x]);
  float s = hv * a_src[threadIdx.x];
  float d = hv * a_dst[threadIdx.x];
  s = blockReduce256(s, buf);
  d = blockReduce256(d, buf);
  if (threadIdx.x == 0) { as_[n] = s; ad_[n] = d; }
}

// ---------------- fused GAT softmax + aggregate: one wave per dst node ----------------
__global__ __launch_bounds__(256) void gat_agg_kernel(
    const int* __restrict__ rowptr, const int* __restrict__ srcS,
    const float* __restrict__ as_, const float* __restrict__ ad_,
    const bf16* __restrict__ h, float* __restrict__ agg) {
  int wid = threadIdx.x >> 6, lane = threadIdx.x & 63;
  int n = blockIdx.x * 4 + wid;
  if (n >= N_NODES) return;
  int start = rowptr[n], end = rowptr[n + 1];
  float adn = ad_[n];
  float m = -1e30f;
  for (int j0 = start; j0 < end; j0 += 64) {
    int j = j0 + lane;
    if (j < end) {
      float e = as_[srcS[j]] + adn;
      e = e > 0.f ? e : 0.2f * e;
      m = fmaxf(m, e);
    }
  }
#pragma unroll
  for (int o = 32; o > 0; o >>= 1) m = fmaxf(m, __shfl_xor(m, o));
  float ssum = 0.f;
  for (int j0 = start; j0 < end; j0 += 64) {
    int j = j0 + lane;
    if (j < end) {
      float e = as_[srcS[j]] + adn;
      e = e > 0.f ? e : 0.2f * e;
      ssum += __expf(e - m);
    }
  }
#pragma unroll
  for (int o = 32; o > 0; o >>= 1) ssum += __shfl_xor(ssum, o);
  float inv = 1.f / ssum;
  float a0 = 0.f, a1 = 0.f, a2 = 0.f, a3 = 0.f;
  const unsigned short* hp = (const unsigned short*)h;
  for (int j = start; j < end; ++j) {
    int s = srcS[j];
    float e = as_[s] + adn;
    e = e > 0.f ? e : 0.2f * e;
    float attn = __expf(e - m) * inv;
    const ushort4 hv = *(const ushort4*)(hp + (size_t)s * D_HID + lane * 4);
    a0 += us2f(hv.x) * attn;
    a1 += us2f(hv.y) * attn;
    a2 += us2f(hv.z) * attn;
    a3 += us2f(hv.w) * attn;
  }
  float4 o4 = {a0, a1, a2, a3};
  *(float4*)(agg + (size_t)n * D_HID + lane * 4) = o4;
}

// ---------------- batch norm (training stats) ----------------
__global__ __launch_bounds__(256) void bn_stats_kernel(
    const float* __restrict__ h, float* __restrict__ sums, float* __restrict__ sumsq) {
  int col = threadIdx.x;
  float s = 0.f, q = 0.f;
  for (int r = blockIdx.x; r < N_NODES; r += gridDim.x) {
    float v = h[(size_t)r * D_HID + col];
    s += v; q += v * v;
  }
  atomicAdd(&sums[col], s);
  atomicAdd(&sumsq[col], q);
}

__global__ __launch_bounds__(256) void bn_finalize_kernel(
    const float* __restrict__ sums, const float* __restrict__ sumsq,
    const float* __restrict__ gamma, const float* __restrict__ beta,
    float* __restrict__ scale, float* __restrict__ shift) {
  int c = threadIdx.x;
  float mu = sums[c] / N_NODES;
  float var = fmaxf(sumsq[c] / N_NODES - mu * mu, 0.f);
  float sc = gamma[c] * rsqrtf(var + 1e-5f);
  scale[c] = sc;
  shift[c] = beta[c] - mu * sc;
}

// ---------------- mean pool (node_batch sorted) + b2 + relu ----------------
__global__ __launch_bounds__(256) void pool_kernel(
    const float* __restrict__ h, const float* __restrict__ bias2,
    const int* __restrict__ nb, float* __restrict__ pooled) {
  int col = threadIdx.x;
  float bias = bias2[col];
  int chunk = (N_NODES + gridDim.x - 1) / gridDim.x;
  int r0 = blockIdx.x * chunk;
  int r1 = min(N_NODES, r0 + chunk);
  float acc = 0.f; int cur = -1;
  for (int r = r0; r < r1; ++r) {
    int g = nb[r];
    if (g != cur) {
      if (cur >= 0) atomicAdd(&pooled[(size_t)cur * D_HID + col], acc);
      acc = 0.f; cur = g;
    }
    acc += fmaxf(h[(size_t)r * D_HID + col] + bias, 0.f);
  }
  if (cur >= 0) atomicAdd(&pooled[(size_t)cur * D_HID + col], acc);
}

__global__ __launch_bounds__(256) void count_kernel(
    const int* __restrict__ nb, float* __restrict__ counts) {
  __shared__ int cnt[N_GRAPHS];
  for (int i = threadIdx.x; i < N_GRAPHS; i += 256) cnt[i] = 0;
  __syncthreads();
  int n = blockIdx.x * 256 + threadIdx.x;
  if (n < N_NODES) atomicAdd(&cnt[nb[n]], 1);
  __syncthreads();
  for (int i = threadIdx.x; i < N_GRAPHS; i += 256)
    if (cnt[i]) atomicAdd(&counts[i], (float)cnt[i]);
}

// ---------------- classifier (OUTPUT FP32) ----------------
__global__ __launch_bounds__(256) void clf_kernel(
    const float* __restrict__ pooled, const float* __restrict__ counts,
    const float* __restrict__ claim, const float* __restrict__ clfW,
    const float* __restrict__ clfb, float* __restrict__ out) {
  __shared__ float buf[4];
  int g = blockIdx.x;
  float inv = 1.f / fmaxf(counts[g], 1.f);
  float p = 0.f;
  for (int d = threadIdx.x; d < (D_HID + D_IN); d += 256) {
    float w = clfW[d];
    float v = (d < D_HID) ? pooled[(size_t)g * D_HID + d] * inv
                          : claim[(size_t)g * D_IN + (d - D_HID)];
    p += v * w;
  }
  p = blockReduce256(p, buf);
  if (threadIdx.x == 0) out[g] = p + clfb[0];
}

extern "C" void kernel_launch(void* const* d_in, const int* in_sizes, int n_in,
                              void* d_out, int out_size, void* d_ws, size_t ws_size,
                              hipStream_t stream) {
  const float* claim = (const float*)d_in[0];
  const float* x     = (const float*)d_in[1];
  const void*  edge  = d_in[2];
  const void*  nbin  = d_in[3];
  const float* W1    = (const float*)d_in[4];
  const float* as1   = (const float*)d_in[5];
  const float* ad1   = (const float*)d_in[6];
  // d_in[7] = b1: cancels in BatchNorm
  const float* W2    = (const float*)d_in[8];
  const float* as2   = (const float*)d_in[9];
  const float* ad2   = (const float*)d_in[10];
  const float* b2v   = (const float*)d_in[11];
  const float* gamma = (const float*)d_in[12];
  const float* beta  = (const float*)d_in[13];
  const float* clfW  = (const float*)d_in[14];
  const float* clfb  = (const float*)d_in[15];
  float* out = (float*)d_out;

  char* wsb = (char*)d_ws;
  size_t off = 0;
  auto alloc = [&](size_t bytes) -> char* {
    char* p = wsb + off;
    off = (off + bytes + 255) & ~(size_t)255;
    return p;
  };
  int*   flagNZ = (int*)alloc(sizeof(int));
  int*   src32  = (int*)alloc((size_t)N_EDGES * sizeof(int));
  int*   dst32  = (int*)alloc((size_t)N_EDGES * sizeof(int));
  int*   nb32   = (int*)alloc((size_t)N_NODES * sizeof(int));
  int*   deg    = (int*)alloc((size_t)N_NODES * sizeof(int));
  int*   rowptr = (int*)alloc((size_t)(N_NODES + 1) * sizeof(int));
  int*   pos    = (int*)alloc((size_t)N_NODES * sizeof(int));
  int*   srcS   = (int*)alloc((size_t)E_TOT * sizeof(int));
  short* W1T    = (short*)alloc((size_t)D_IN * D_HID * sizeof(short));
  short* W2T    = (short*)alloc((size_t)D_HID * D_HID * sizeof(short));
  float* rel    = (float*)alloc((size_t)N_NODES * sizeof(float));
  float* alphas = (float*)alloc((size_t)N_NODES * sizeof(float));
  float* alphad = (float*)alloc((size_t)N_NODES * sizeof(float));
  float* bnsums = (float*)alloc(D_HID * sizeof(float));
  float* bnsq   = (float*)alloc(D_HID * sizeof(float));
  float* bnscale= (float*)alloc(D_HID * sizeof(float));
  float* bnshift= (float*)alloc(D_HID * sizeof(float));
  float* pooled = (float*)alloc((size_t)N_GRAPHS * D_HID * sizeof(float));
  float* counts = (float*)alloc((size_t)N_GRAPHS * sizeof(float));
  float* agg    = (float*)alloc((size_t)N_NODES * D_HID * sizeof(float));
  bf16*  h      = (bf16*) alloc((size_t)N_NODES * D_HID * sizeof(bf16));

  // ---- index normalization + CSR build ----
  hipMemsetAsync(flagNZ, 0, sizeof(int), stream);
  detect_idx_kernel<<<1, 256, 0, stream>>>((const int*)edge, flagNZ);
  normalize_idx_kernel<<<(N_EDGES + N_NODES + 255) / 256, 256, 0, stream>>>(
      edge, nbin, flagNZ, src32, dst32, nb32);
  hipMemsetAsync(deg, 0, (size_t)N_NODES * sizeof(int), stream);
  int egrid = (E_TOT + 255) / 256;
  hist_kernel<<<egrid, 256, 0, stream>>>(dst32, deg);
  scan_kernel<<<1, 256, 0, stream>>>(deg, rowptr, pos);
  scatter_kernel<<<egrid, 256, 0, stream>>>(src32, dst32, pos, srcS);

  // ---- weights -> transposed bf16 (once) ----
  convert_wt_kernel<<<(D_IN * D_HID + 255) / 256, 256, 0, stream>>>(W1, W1T, D_IN, D_HID);
  convert_wt_kernel<<<(D_HID * D_HID + 255) / 256, 256, 0, stream>>>(W2, W2T, D_HID, D_HID);

  hipMemsetAsync(bnsums, 0, D_HID * 4, stream);
  hipMemsetAsync(bnsq, 0, D_HID * 4, stream);
  hipMemsetAsync(pooled, 0, (size_t)N_GRAPHS * D_HID * 4, stream);
  hipMemsetAsync(counts, 0, (size_t)N_GRAPHS * 4, stream);

  int gemmGrid = (N_NODES + 63) / 64;

  // ---- layer 1 ----
  rel_kernel<<<N_NODES, 256, 0, stream>>>(x, claim, nb32, rel);
  mfma_gemm_kernel<0><<<gemmGrid, 256, 0, stream>>>(x, W1T, rel, nullptr, nullptr, h, N_NODES, D_IN);
  alpha_kernel<<<N_NODES, 256, 0, stream>>>(h, as1, ad1, alphas, alphad);
  gat_agg_kernel<<<N_NODES / 4, 256, 0, stream>>>(rowptr, srcS, alphas, alphad, h, agg);

  bn_stats_kernel<<<256, 256, 0, stream>>>(agg, bnsums, bnsq);
  bn_finalize_kernel<<<1, 256, 0, stream>>>(bnsums, bnsq, gamma, beta, bnscale, bnshift);

  // ---- layer 2 (BN+ReLU fused into A-staging) ----
  mfma_gemm_kernel<1><<<gemmGrid, 256, 0, stream>>>(agg, W2T, nullptr, bnscale, bnshift, h, N_NODES, D_HID);
  alpha_kernel<<<N_NODES, 256, 0, stream>>>(h, as2, ad2, alphas, alphad);
  gat_agg_kernel<<<N_NODES / 4, 256, 0, stream>>>(rowptr, srcS, alphas, alphad, h, agg);

  // ---- pool + classifier ----
  pool_kernel<<<256, 256, 0, stream>>>(agg, b2v, nb32, pooled);
  count_kernel<<<(N_NODES + 255) / 256, 256, 0, stream>>>(nb32, counts);
  clf_kernel<<<N_GRAPHS, 256, 0, stream>>>(pooled, counts, claim, clfW, clfb, out);
}